// Round 4
// baseline (1489.712 us; speedup 1.0000x reference)
//
#include <hip/hip_runtime.h>
#include <stdint.h>

#define T_    16
#define N_    2048
#define CAP_  96

__device__ inline float frcp(float x){
#if __has_builtin(__builtin_amdgcn_rcpf)
  return __builtin_amdgcn_rcpf(x);
#else
  return 1.0f / x;
#endif
}
__device__ inline float fsig(float x){ return frcp(1.0f + __expf(-x)); }

// ---------------------------------------------------------------- mask build + cnt zero
__global__ __launch_bounds__(256) void k_mask(const uint8_t* __restrict__ ego_raw,
                                              float* __restrict__ m,
                                              int* __restrict__ cnt){
  __shared__ int s_int01, s_f01;
  const int tid = threadIdx.x;
  if (tid == 0){ s_int01 = 1; s_f01 = 1; }
  __syncthreads();
  const uint32_t* w = (const uint32_t*)ego_raw;
  int int01 = 1, f01 = 1;
  for (int i = tid; i < 8192; i += 256){
    uint32_t v = w[i];
    int01 &= (v <= 1u);
    f01   &= (v == 0u) || (v == 0x3F800000u);
  }
  if (!int01) atomicAnd(&s_int01, 0);
  if (!f01)   atomicAnd(&s_f01, 0);
  __syncthreads();
  const int mode = s_int01 ? 0 : (s_f01 ? 1 : 2); // 0:int32 1:f32 2:byte
  const int base = blockIdx.x * 2048;
  for (int q = tid; q < 2048; q += 256){
    int i = base + q;
    int t = i >> 11, n = i & 2047, b = n >> 8, j = n & 255;
    int src = (b*T_ + t)*256 + j;
    float val;
    if (mode == 0)      val = (((const int32_t*)ego_raw)[src] != 0)   ? 1.f : 0.f;
    else if (mode == 1) val = (((const float*)ego_raw)[src]  != 0.f)  ? 1.f : 0.f;
    else                val = (ego_raw[src] != 0)                     ? 1.f : 0.f;
    m[i] = val;
    cnt[i] = 0;
  }
}

// ---------------------------------------------------------------- sparsify adj into CSC lists
// Contiguous streaming: each block owns a 256 KB contiguous slab, float4 loads.
__global__ __launch_bounds__(256) void k_sparsify(const float* __restrict__ adj,
                                                  int* __restrict__ cnt,
                                                  uint16_t* __restrict__ idx){
  const int bx = blockIdx.x;           // 1024 blocks
  const int t  = bx >> 6;              // 0..15
  const int sg = bx & 63;              // 0..63, 32 s-rows each
  const int tid = threadIdx.x;
  const int tcol = t << 11;
  const float4* base4 = (const float4*)(adj + ((size_t)t << 22));
  for (int sr = 0; sr < 32; sr++){
    int s = (sg << 5) + sr;
    const float4* row4 = base4 + ((size_t)s << 9);
    #pragma unroll
    for (int ii = 0; ii < 2; ii++){
      float4 v = row4[(ii << 8) + tid];
      int d = ((ii << 8) + tid) << 2;
      if (v.x != 0.f){ int p = atomicAdd(&cnt[tcol+d  ],1); if (p<CAP_) idx[(size_t)(tcol+d  )*CAP_+p]=(uint16_t)s; }
      if (v.y != 0.f){ int p = atomicAdd(&cnt[tcol+d+1],1); if (p<CAP_) idx[(size_t)(tcol+d+1)*CAP_+p]=(uint16_t)s; }
      if (v.z != 0.f){ int p = atomicAdd(&cnt[tcol+d+2],1); if (p<CAP_) idx[(size_t)(tcol+d+2)*CAP_+p]=(uint16_t)s; }
      if (v.w != 0.f){ int p = atomicAdd(&cnt[tcol+d+3],1); if (p<CAP_) idx[(size_t)(tcol+d+3)*CAP_+p]=(uint16_t)s; }
    }
  }
}

// ---------------------------------------------------------------- dinv
__global__ __launch_bounds__(256) void k_dinv(const int* __restrict__ cnt,
                                              const uint16_t* __restrict__ idx,
                                              const float* __restrict__ m,
                                              float* __restrict__ dinv){
  const int col = blockIdx.x*256 + threadIdx.x;
  int c = cnt[col]; if (c > CAP_) c = CAP_;
  const int tbase = col & ~2047;
  const uint16_t* lst = idx + (size_t)col*CAP_;
  float s = 1.0f;                       // self-loop
  for (int i = 0; i < c; i++) s += m[tbase + lst[i]];
  dinv[col] = (m[col] > 0.5f) ? rsqrtf(s) : 0.f;
}

// ---------------------------------------------------------------- layer 1 fused: h1 = relu(dinv*Σ dinv_s*(x_s@W1) + b1)
__global__ __launch_bounds__(256) void k_gcn1(const float* __restrict__ x,
                                              const float* __restrict__ W1,
                                              const float* __restrict__ b1,
                                              const int* __restrict__ cnt,
                                              const uint16_t* __restrict__ idx,
                                              const float* __restrict__ dinv,
                                              float* __restrict__ h1){
  const int col = blockIdx.x*4 + (threadIdx.x >> 6);
  const int lane = threadIdx.x & 63;
  int c = cnt[col]; if (c > CAP_) c = CAP_;
  const int tbase = col & ~2047;
  const uint16_t* lst = idx + (size_t)col*CAP_;
  const float w1a = W1[lane], w1b = W1[64 + lane];
  const float2* x2 = (const float2*)x;
  float2 xs = x2[col];
  float acc = dinv[col]*(xs.x*w1a + xs.y*w1b);     // self-loop
  for (int i = 0; i < c; i++){
    int s = tbase + lst[i];
    float ds = dinv[s];
    float2 xv = x2[s];
    acc += ds*(xv.x*w1a + xv.y*w1b);
  }
  float y = dinv[col]*acc + b1[lane];
  h1[(size_t)col*64 + lane] = fmaxf(y, 0.f);
}

// ---------------------------------------------------------------- v2 = dinv * (h1 @ W2)
__global__ __launch_bounds__(256) void k_v2(const float* __restrict__ h1,
                                            const float* __restrict__ W2,
                                            const float* __restrict__ dinv,
                                            float* __restrict__ v2){
  const int gid = blockIdx.x*256 + threadIdx.x;   // node*64 + hp
  const int hp = gid & 63, node = gid >> 6;
  const float* row = h1 + (size_t)node*64;
  float s = 0.f;
  #pragma unroll 8
  for (int h = 0; h < 64; h++) s += row[h]*W2[h*64 + hp];
  v2[gid] = dinv[node]*s;
}

// ---------------------------------------------------------------- layer 2 aggregation: h2 = m * (dinv*Σ v2 + b2)
__global__ __launch_bounds__(256) void k_agg2(const float* __restrict__ v,
                                              const int* __restrict__ cnt,
                                              const uint16_t* __restrict__ idx,
                                              const float* __restrict__ dinv,
                                              const float* __restrict__ m,
                                              const float* __restrict__ b2,
                                              float* __restrict__ h2){
  const int col = blockIdx.x*4 + (threadIdx.x >> 6);
  const int lane = threadIdx.x & 63;
  int c = cnt[col]; if (c > CAP_) c = CAP_;
  const int tbase = col & ~2047;
  const uint16_t* lst = idx + (size_t)col*CAP_;
  float acc = v[(size_t)col*64 + lane];            // self-loop
  for (int i = 0; i < c; i++){
    int s = lst[i];
    acc += v[((size_t)tbase + s)*64 + lane];
  }
  float y = dinv[col]*acc + b2[lane];
  h2[(size_t)col*64 + lane] = m[col]*y;
}

// ---------------------------------------------------------------- P4[tn][j][gate] pre-activations
// Weights held in VGPRs; h2 rows wave-uniform broadcast float4 loads.
__global__ __launch_bounds__(256) void k_lstmpre(const float* __restrict__ h2,
                                                 const float* __restrict__ Wih,
                                                 const float* __restrict__ bih,
                                                 const float* __restrict__ bhh,
                                                 float* __restrict__ P4){
  const int tid = threadIdx.x;
  const int j = tid & 127;                         // gate row 0..127
  const int half = tid >> 7;                       // 0/1
  const int tn0 = blockIdx.x*64 + half*32;
  float wr[64];
  const float* wsrc = Wih + j*64;
  #pragma unroll
  for (int k = 0; k < 64; k++) wr[k] = wsrc[k];
  const float bj = bih[j] + bhh[j];
  const int dst = (j & 31)*4 + (j >> 5);           // interleaved {i,f,g,o} per jj
  for (int r = 0; r < 32; r++){
    int tn = tn0 + r;
    const float4* row = (const float4*)(h2 + (size_t)tn*64);
    float a0 = bj, a1 = 0.f, a2 = 0.f, a3 = 0.f;
    #pragma unroll
    for (int q = 0; q < 16; q++){
      float4 hv = row[q];
      a0 = fmaf(wr[4*q  ], hv.x, a0);
      a1 = fmaf(wr[4*q+1], hv.y, a1);
      a2 = fmaf(wr[4*q+2], hv.z, a2);
      a3 = fmaf(wr[4*q+3], hv.w, a3);
    }
    P4[(size_t)tn*128 + dst] = (a0 + a1) + (a2 + a3);
  }
}

// ---------------------------------------------------------------- LSTM scan: 16 chains, 1 wave each
// All lanes redundantly compute all 4 gates for j=l&31 (no cross-half
// exchange — measured ~200+ cyc per shfl makes split-gate a net loss).
// h broadcast via LDS: 1 same-address ds_write + 8 ds_read_b128/step
// (replaces 32 v_readlane + SGPR hazards). Single wave → no barriers.
__global__ __launch_bounds__(64, 1) void k_lstm(const float* __restrict__ P4,
                                                const float* __restrict__ Whh,
                                                float* __restrict__ L64){
  const int t = blockIdx.x;       // chain 0..15
  const int l = threadIdx.x;      // 0..63
  const int j = l & 31;
  float wi[32], wf[32], wg[32], wo[32];
  #pragma unroll
  for (int k = 0; k < 32; k++){
    wi[k] = Whh[(     j)*32 + k];
    wf[k] = Whh[(32 + j)*32 + k];
    wg[k] = Whh[(64 + j)*32 + k];
    wo[k] = Whh[(96 + j)*32 + k];
  }
  __shared__ float hs[32];
  hs[j] = 0.f;                    // both halves write identical value
  const float4* Pt = (const float4*)P4 + (size_t)t*N_*32 + j;
  float* Lt = L64 + (size_t)t*N_*64;
  float c = 0.f;
  float4 p0 = Pt[0], p1 = Pt[32];
  for (int n = 0; n < N_; n++){
    float4 cur = p0; p0 = p1;
    int np = (n + 2 < N_) ? (n + 2) : (N_ - 1);
    p1 = Pt[(size_t)np*32];
    float ai0=0.f, ai1=0.f, af0=0.f, af1=0.f;
    float ag0=0.f, ag1=0.f, ao0=0.f, ao1=0.f;
    const float4* h4 = (const float4*)hs;
    #pragma unroll
    for (int q = 0; q < 8; q++){
      float4 hv = h4[q];
      ai0 = fmaf(wi[4*q  ], hv.x, ai0); af0 = fmaf(wf[4*q  ], hv.x, af0);
      ag0 = fmaf(wg[4*q  ], hv.x, ag0); ao0 = fmaf(wo[4*q  ], hv.x, ao0);
      ai1 = fmaf(wi[4*q+1], hv.y, ai1); af1 = fmaf(wf[4*q+1], hv.y, af1);
      ag1 = fmaf(wg[4*q+1], hv.y, ag1); ao1 = fmaf(wo[4*q+1], hv.y, ao1);
      ai0 = fmaf(wi[4*q+2], hv.z, ai0); af0 = fmaf(wf[4*q+2], hv.z, af0);
      ag0 = fmaf(wg[4*q+2], hv.z, ag0); ao0 = fmaf(wo[4*q+2], hv.z, ao0);
      ai1 = fmaf(wi[4*q+3], hv.w, ai1); af1 = fmaf(wf[4*q+3], hv.w, af1);
      ag1 = fmaf(wg[4*q+3], hv.w, ag1); ao1 = fmaf(wo[4*q+3], hv.w, ao1);
    }
    float gi = cur.x + (ai0 + ai1);
    float gf = cur.y + (af0 + af1);
    float gg = cur.z + (ag0 + ag1);
    float go = cur.w + (ao0 + ao1);
    float iv = fsig(gi);
    float fv = fsig(gf);
    float gv = fmaf(2.0f, fsig(2.0f*gg), -1.0f);   // tanh
    float ov = fsig(go);
    c = fmaf(fv, c, iv*gv);
    float th = fmaf(2.0f, fsig(2.0f*c), -1.0f);    // tanh(c)
    float hn = ov*th;
    hs[j] = hn;                                    // broadcast for next step
    Lt[n*64 + l] = hn;                             // full-wave 256B store
  }
}

// ---------------------------------------------------------------- scores[t*2048+n] = lstm[t,n,:]@Wa
__global__ __launch_bounds__(256) void k_score(const float* __restrict__ L64,
                                               const float* __restrict__ Wa,
                                               float* __restrict__ scores){
  const int gid = blockIdx.x*256 + threadIdx.x;   // t*2048 + n, 32768 total
  const float4* row = (const float4*)(L64 + (size_t)gid*64);
  const float4* wa4 = (const float4*)Wa;
  float s = 0.f;
  #pragma unroll
  for (int q = 0; q < 8; q++){
    float4 hv = row[q], wv = wa4[q];
    s += hv.x*wv.x + hv.y*wv.y + hv.z*wv.z + hv.w*wv.w;
  }
  scores[gid] = s;
}

// ---------------------------------------------------------------- softmax attention pool
__global__ __launch_bounds__(256) void k_attn(const float* __restrict__ scores,
                                              const float* __restrict__ L64,
                                              float* __restrict__ out){
  const int gid = blockIdx.x*256 + threadIdx.x;   // n*32 + k
  const int k = gid & 31, n = gid >> 5;
  float sc[16]; float mx = -1e30f;
  #pragma unroll
  for (int t = 0; t < 16; t++){ float v = scores[(t << 11) + n]; sc[t] = v; mx = fmaxf(mx, v); }
  float sum = 0.f;
  #pragma unroll
  for (int t = 0; t < 16; t++){ float e = __expf(sc[t] - mx); sc[t] = e; sum += e; }
  const float inv = frcp(sum);
  float acc = 0.f;
  #pragma unroll
  for (int t = 0; t < 16; t++) acc += sc[t]*L64[((size_t)((t << 11) + n))*64 + k];
  out[gid] = acc*inv;
}

// ---------------------------------------------------------------- launch
extern "C" void kernel_launch(void* const* d_in, const int* in_sizes, int n_in,
                              void* d_out, int out_size, void* d_ws, size_t ws_size,
                              hipStream_t stream){
  (void)in_sizes; (void)n_in; (void)out_size; (void)ws_size;
  const float*   x   = (const float*)d_in[0];
  const float*   adj = (const float*)d_in[1];
  const uint8_t* ego = (const uint8_t*)d_in[2];
  const float*   W1  = (const float*)d_in[3];
  const float*   b1  = (const float*)d_in[4];
  const float*   W2  = (const float*)d_in[5];
  const float*   b2  = (const float*)d_in[6];
  const float*   Wih = (const float*)d_in[7];
  const float*   Whh = (const float*)d_in[8];
  const float*   bih = (const float*)d_in[9];
  const float*   bhh = (const float*)d_in[10];
  const float*   Wa  = (const float*)d_in[11];
  // d_in[12] = ba: softmax is shift-invariant, unused
  float* out = (float*)d_out;
  char* ws = (char*)d_ws;

  float*    m      = (float*)(ws);                  // 128 KB
  float*    dinv   = (float*)(ws + 131072);         // 128 KB
  int*      cnt    = (int*)  (ws + 262144);         // 128 KB
  uint16_t* idx    = (uint16_t*)(ws + 393216);      // 6 MB
  float*    v      = (float*)(ws + 6684672);        // 8 MB   (v2; later reused as L64)
  float*    h      = (float*)(ws + 15073280);       // 8 MB   (h1 then h2; later scores)
  float*    P4     = (float*)(ws + 23461888);       // 16 MB
  float*    L64    = v;                             // v dead after k_agg2
  float*    scores = h;                             // h dead after k_lstmpre

  k_mask    <<<16,    256, 0, stream>>>(ego, m, cnt);
  k_sparsify<<<1024,  256, 0, stream>>>(adj, cnt, idx);
  k_dinv    <<<128,   256, 0, stream>>>(cnt, idx, m, dinv);
  k_gcn1    <<<8192,  256, 0, stream>>>(x, W1, b1, cnt, idx, dinv, h);
  k_v2      <<<8192,  256, 0, stream>>>(h, W2, dinv, v);
  k_agg2    <<<8192,  256, 0, stream>>>(v, cnt, idx, dinv, m, b2, h);
  k_lstmpre <<<512,   256, 0, stream>>>(h, Wih, bih, bhh, P4);
  k_lstm    <<<16,    64,  0, stream>>>(P4, Whh, L64);
  k_score   <<<128,   256, 0, stream>>>(L64, Wa, scores);
  k_attn    <<<256,   256, 0, stream>>>(scores, L64, out);
}

// Round 5
// 1284.396 us; speedup vs baseline: 1.1599x; 1.1599x over previous
//
#include <hip/hip_runtime.h>
#include <stdint.h>

#define T_    16
#define N_    2048
#define CAP_  96

typedef float v2f __attribute__((ext_vector_type(2)));

__device__ inline float frcp(float x){
#if __has_builtin(__builtin_amdgcn_rcpf)
  return __builtin_amdgcn_rcpf(x);
#else
  return 1.0f / x;
#endif
}
__device__ inline float fsig(float x){ return frcp(1.0f + __expf(-x)); }
__device__ inline float rdlane(float v, int k){
  return __int_as_float(__builtin_amdgcn_readlane(__float_as_int(v), k));
}

// ---------------------------------------------------------------- mask build + cnt zero
__global__ __launch_bounds__(256) void k_mask(const uint8_t* __restrict__ ego_raw,
                                              float* __restrict__ m,
                                              int* __restrict__ cnt){
  __shared__ int s_int01, s_f01;
  const int tid = threadIdx.x;
  if (tid == 0){ s_int01 = 1; s_f01 = 1; }
  __syncthreads();
  const uint32_t* w = (const uint32_t*)ego_raw;
  int int01 = 1, f01 = 1;
  for (int i = tid; i < 8192; i += 256){
    uint32_t v = w[i];
    int01 &= (v <= 1u);
    f01   &= (v == 0u) || (v == 0x3F800000u);
  }
  if (!int01) atomicAnd(&s_int01, 0);
  if (!f01)   atomicAnd(&s_f01, 0);
  __syncthreads();
  const int mode = s_int01 ? 0 : (s_f01 ? 1 : 2); // 0:int32 1:f32 2:byte
  const int base = blockIdx.x * 2048;
  for (int q = tid; q < 2048; q += 256){
    int i = base + q;
    int t = i >> 11, n = i & 2047, b = n >> 8, j = n & 255;
    int src = (b*T_ + t)*256 + j;
    float val;
    if (mode == 0)      val = (((const int32_t*)ego_raw)[src] != 0)   ? 1.f : 0.f;
    else if (mode == 1) val = (((const float*)ego_raw)[src]  != 0.f)  ? 1.f : 0.f;
    else                val = (ego_raw[src] != 0)                     ? 1.f : 0.f;
    m[i] = val;
    cnt[i] = 0;
  }
}

// ---------------------------------------------------------------- sparsify adj into CSC lists
// Contiguous streaming: each block owns a 256 KB contiguous slab, float4 loads.
__global__ __launch_bounds__(256) void k_sparsify(const float* __restrict__ adj,
                                                  int* __restrict__ cnt,
                                                  uint16_t* __restrict__ idx){
  const int bx = blockIdx.x;           // 1024 blocks
  const int t  = bx >> 6;              // 0..15
  const int sg = bx & 63;              // 0..63, 32 s-rows each
  const int tid = threadIdx.x;
  const int tcol = t << 11;
  const float4* base4 = (const float4*)(adj + ((size_t)t << 22));
  for (int sr = 0; sr < 32; sr++){
    int s = (sg << 5) + sr;
    const float4* row4 = base4 + ((size_t)s << 9);
    #pragma unroll
    for (int ii = 0; ii < 2; ii++){
      float4 v = row4[(ii << 8) + tid];
      int d = ((ii << 8) + tid) << 2;
      if (v.x != 0.f){ int p = atomicAdd(&cnt[tcol+d  ],1); if (p<CAP_) idx[(size_t)(tcol+d  )*CAP_+p]=(uint16_t)s; }
      if (v.y != 0.f){ int p = atomicAdd(&cnt[tcol+d+1],1); if (p<CAP_) idx[(size_t)(tcol+d+1)*CAP_+p]=(uint16_t)s; }
      if (v.z != 0.f){ int p = atomicAdd(&cnt[tcol+d+2],1); if (p<CAP_) idx[(size_t)(tcol+d+2)*CAP_+p]=(uint16_t)s; }
      if (v.w != 0.f){ int p = atomicAdd(&cnt[tcol+d+3],1); if (p<CAP_) idx[(size_t)(tcol+d+3)*CAP_+p]=(uint16_t)s; }
    }
  }
}

// ---------------------------------------------------------------- dinv
__global__ __launch_bounds__(256) void k_dinv(const int* __restrict__ cnt,
                                              const uint16_t* __restrict__ idx,
                                              const float* __restrict__ m,
                                              float* __restrict__ dinv){
  const int col = blockIdx.x*256 + threadIdx.x;
  int c = cnt[col]; if (c > CAP_) c = CAP_;
  const int tbase = col & ~2047;
  const uint16_t* lst = idx + (size_t)col*CAP_;
  float s = 1.0f;                       // self-loop
  for (int i = 0; i < c; i++) s += m[tbase + lst[i]];
  dinv[col] = (m[col] > 0.5f) ? rsqrtf(s) : 0.f;
}

// ---------------------------------------------------------------- layer 1 fused: h1 = relu(dinv*Σ dinv_s*(x_s@W1) + b1)
__global__ __launch_bounds__(256) void k_gcn1(const float* __restrict__ x,
                                              const float* __restrict__ W1,
                                              const float* __restrict__ b1,
                                              const int* __restrict__ cnt,
                                              const uint16_t* __restrict__ idx,
                                              const float* __restrict__ dinv,
                                              float* __restrict__ h1){
  const int col = blockIdx.x*4 + (threadIdx.x >> 6);
  const int lane = threadIdx.x & 63;
  int c = cnt[col]; if (c > CAP_) c = CAP_;
  const int tbase = col & ~2047;
  const uint16_t* lst = idx + (size_t)col*CAP_;
  const float w1a = W1[lane], w1b = W1[64 + lane];
  const float2* x2 = (const float2*)x;
  float2 xs = x2[col];
  float acc = dinv[col]*(xs.x*w1a + xs.y*w1b);     // self-loop
  for (int i = 0; i < c; i++){
    int s = tbase + lst[i];
    float ds = dinv[s];
    float2 xv = x2[s];
    acc += ds*(xv.x*w1a + xv.y*w1b);
  }
  float y = dinv[col]*acc + b1[lane];
  h1[(size_t)col*64 + lane] = fmaxf(y, 0.f);
}

// ---------------------------------------------------------------- v2 = dinv * (h1 @ W2)
__global__ __launch_bounds__(256) void k_v2(const float* __restrict__ h1,
                                            const float* __restrict__ W2,
                                            const float* __restrict__ dinv,
                                            float* __restrict__ v2){
  const int gid = blockIdx.x*256 + threadIdx.x;   // node*64 + hp
  const int hp = gid & 63, node = gid >> 6;
  const float* row = h1 + (size_t)node*64;
  float s = 0.f;
  #pragma unroll 8
  for (int h = 0; h < 64; h++) s += row[h]*W2[h*64 + hp];
  v2[gid] = dinv[node]*s;
}

// ---------------------------------------------------------------- layer 2 aggregation: h2 = m * (dinv*Σ v2 + b2)
__global__ __launch_bounds__(256) void k_agg2(const float* __restrict__ v,
                                              const int* __restrict__ cnt,
                                              const uint16_t* __restrict__ idx,
                                              const float* __restrict__ dinv,
                                              const float* __restrict__ m,
                                              const float* __restrict__ b2,
                                              float* __restrict__ h2){
  const int col = blockIdx.x*4 + (threadIdx.x >> 6);
  const int lane = threadIdx.x & 63;
  int c = cnt[col]; if (c > CAP_) c = CAP_;
  const int tbase = col & ~2047;
  const uint16_t* lst = idx + (size_t)col*CAP_;
  float acc = v[(size_t)col*64 + lane];            // self-loop
  for (int i = 0; i < c; i++){
    int s = lst[i];
    acc += v[((size_t)tbase + s)*64 + lane];
  }
  float y = dinv[col]*acc + b2[lane];
  h2[(size_t)col*64 + lane] = m[col]*y;
}

// ---------------------------------------------------------------- P4[tn][j][gate] pre-activations
// Weights held in VGPRs; h2 rows wave-uniform broadcast float4 loads.
__global__ __launch_bounds__(256) void k_lstmpre(const float* __restrict__ h2,
                                                 const float* __restrict__ Wih,
                                                 const float* __restrict__ bih,
                                                 const float* __restrict__ bhh,
                                                 float* __restrict__ P4){
  const int tid = threadIdx.x;
  const int j = tid & 127;                         // gate row 0..127
  const int half = tid >> 7;                       // 0/1
  const int tn0 = blockIdx.x*64 + half*32;
  float wr[64];
  const float* wsrc = Wih + j*64;
  #pragma unroll
  for (int k = 0; k < 64; k++) wr[k] = wsrc[k];
  const float bj = bih[j] + bhh[j];
  const int dst = (j & 31)*4 + (j >> 5);           // interleaved {i,f,g,o} per jj
  for (int r = 0; r < 32; r++){
    int tn = tn0 + r;
    const float4* row = (const float4*)(h2 + (size_t)tn*64);
    float a0 = bj, a1 = 0.f, a2 = 0.f, a3 = 0.f;
    #pragma unroll
    for (int q = 0; q < 16; q++){
      float4 hv = row[q];
      a0 = fmaf(wr[4*q  ], hv.x, a0);
      a1 = fmaf(wr[4*q+1], hv.y, a1);
      a2 = fmaf(wr[4*q+2], hv.z, a2);
      a3 = fmaf(wr[4*q+3], hv.w, a3);
    }
    P4[(size_t)tn*128 + dst] = (a0 + a1) + (a2 + a3);
  }
}

// ---------------------------------------------------------------- LSTM scan: 16 chains, 1 wave each
// R3 readlane structure (LDS broadcast measured +270 cyc/step — reverted).
// Gate accumulation packed as (i,f) and (g,o) v2f pairs so LLVM selects
// v_pk_fma_f32 — halves FMA issue from 128 to 64 instrs/step.
__global__ __launch_bounds__(64, 1) void k_lstm(const float* __restrict__ P4,
                                                const float* __restrict__ Whh,
                                                float* __restrict__ L64){
  const int t = blockIdx.x;       // chain 0..15
  const int l = threadIdx.x;      // 0..63
  const int j = l & 31;
  v2f wif[32], wgo[32];
  #pragma unroll
  for (int k = 0; k < 32; k++){
    wif[k] = (v2f){ Whh[(     j)*32 + k], Whh[(32 + j)*32 + k] };
    wgo[k] = (v2f){ Whh[(64 + j)*32 + k], Whh[(96 + j)*32 + k] };
  }
  const float4* Pt = (const float4*)P4 + (size_t)t*N_*32 + j;
  float* Lt = L64 + (size_t)t*N_*64;
  float c = 0.f, hn = 0.f;
  float4 p0 = Pt[0], p1 = Pt[32];
  for (int n = 0; n < N_; n++){
    float4 cur = p0; p0 = p1;
    int np = (n + 2 < N_) ? (n + 2) : (N_ - 1);
    p1 = Pt[(size_t)np*32];
    v2f aif0 = (v2f){0.f,0.f}, aif1 = aif0, ago0 = aif0, ago1 = aif0;
    #pragma unroll
    for (int k = 0; k < 32; k += 2){
      float h0 = rdlane(hn, k), h1 = rdlane(hn, k+1);
      v2f h00 = (v2f){h0, h0}, h11 = (v2f){h1, h1};
      aif0 = __builtin_elementwise_fma(wif[k  ], h00, aif0);
      ago0 = __builtin_elementwise_fma(wgo[k  ], h00, ago0);
      aif1 = __builtin_elementwise_fma(wif[k+1], h11, aif1);
      ago1 = __builtin_elementwise_fma(wgo[k+1], h11, ago1);
    }
    v2f gif = (v2f){cur.x, cur.y} + (aif0 + aif1);
    v2f ggo = (v2f){cur.z, cur.w} + (ago0 + ago1);
    float iv = fsig(gif.x);
    float fv = fsig(gif.y);
    float gv = fmaf(2.0f, fsig(2.0f*ggo.x), -1.0f);   // tanh
    float ov = fsig(ggo.y);
    c = fmaf(fv, c, iv*gv);
    float th = fmaf(2.0f, fsig(2.0f*c), -1.0f);       // tanh(c)
    hn = ov*th;
    Lt[n*64 + l] = hn;                                // full-wave 256B store
  }
}

// ---------------------------------------------------------------- scores[t*2048+n] = lstm[t,n,:]@Wa
__global__ __launch_bounds__(256) void k_score(const float* __restrict__ L64,
                                               const float* __restrict__ Wa,
                                               float* __restrict__ scores){
  const int gid = blockIdx.x*256 + threadIdx.x;   // t*2048 + n, 32768 total
  const float4* row = (const float4*)(L64 + (size_t)gid*64);
  const float4* wa4 = (const float4*)Wa;
  float s = 0.f;
  #pragma unroll
  for (int q = 0; q < 8; q++){
    float4 hv = row[q], wv = wa4[q];
    s += hv.x*wv.x + hv.y*wv.y + hv.z*wv.z + hv.w*wv.w;
  }
  scores[gid] = s;
}

// ---------------------------------------------------------------- softmax attention pool
__global__ __launch_bounds__(256) void k_attn(const float* __restrict__ scores,
                                              const float* __restrict__ L64,
                                              float* __restrict__ out){
  const int gid = blockIdx.x*256 + threadIdx.x;   // n*32 + k
  const int k = gid & 31, n = gid >> 5;
  float sc[16]; float mx = -1e30f;
  #pragma unroll
  for (int t = 0; t < 16; t++){ float v = scores[(t << 11) + n]; sc[t] = v; mx = fmaxf(mx, v); }
  float sum = 0.f;
  #pragma unroll
  for (int t = 0; t < 16; t++){ float e = __expf(sc[t] - mx); sc[t] = e; sum += e; }
  const float inv = frcp(sum);
  float acc = 0.f;
  #pragma unroll
  for (int t = 0; t < 16; t++) acc += sc[t]*L64[((size_t)((t << 11) + n))*64 + k];
  out[gid] = acc*inv;
}

// ---------------------------------------------------------------- launch
extern "C" void kernel_launch(void* const* d_in, const int* in_sizes, int n_in,
                              void* d_out, int out_size, void* d_ws, size_t ws_size,
                              hipStream_t stream){
  (void)in_sizes; (void)n_in; (void)out_size; (void)ws_size;
  const float*   x   = (const float*)d_in[0];
  const float*   adj = (const float*)d_in[1];
  const uint8_t* ego = (const uint8_t*)d_in[2];
  const float*   W1  = (const float*)d_in[3];
  const float*   b1  = (const float*)d_in[4];
  const float*   W2  = (const float*)d_in[5];
  const float*   b2  = (const float*)d_in[6];
  const float*   Wih = (const float*)d_in[7];
  const float*   Whh = (const float*)d_in[8];
  const float*   bih = (const float*)d_in[9];
  const float*   bhh = (const float*)d_in[10];
  const float*   Wa  = (const float*)d_in[11];
  // d_in[12] = ba: softmax is shift-invariant, unused
  float* out = (float*)d_out;
  char* ws = (char*)d_ws;

  float*    m      = (float*)(ws);                  // 128 KB
  float*    dinv   = (float*)(ws + 131072);         // 128 KB
  int*      cnt    = (int*)  (ws + 262144);         // 128 KB
  uint16_t* idx    = (uint16_t*)(ws + 393216);      // 6 MB
  float*    v      = (float*)(ws + 6684672);        // 8 MB   (v2; later reused as L64)
  float*    h      = (float*)(ws + 15073280);       // 8 MB   (h1 then h2; later scores)
  float*    P4     = (float*)(ws + 23461888);       // 16 MB
  float*    L64    = v;                             // v dead after k_agg2
  float*    scores = h;                             // h dead after k_lstmpre

  k_mask    <<<16,    256, 0, stream>>>(ego, m, cnt);
  k_sparsify<<<1024,  256, 0, stream>>>(adj, cnt, idx);
  k_dinv    <<<128,   256, 0, stream>>>(cnt, idx, m, dinv);
  k_gcn1    <<<8192,  256, 0, stream>>>(x, W1, b1, cnt, idx, dinv, h);
  k_v2      <<<8192,  256, 0, stream>>>(h, W2, dinv, v);
  k_agg2    <<<8192,  256, 0, stream>>>(v, cnt, idx, dinv, m, b2, h);
  k_lstmpre <<<512,   256, 0, stream>>>(h, Wih, bih, bhh, P4);
  k_lstm    <<<16,    64,  0, stream>>>(P4, Whh, L64);
  k_score   <<<128,   256, 0, stream>>>(L64, Wa, scores);
  k_attn    <<<256,   256, 0, stream>>>(scores, L64, out);
}